// Round 1
// baseline (453.502 us; speedup 1.0000x reference)
//
#include <hip/hip_runtime.h>

typedef __bf16 bf16x8 __attribute__((ext_vector_type(8)));
typedef float floatx4 __attribute__((ext_vector_type(4)));

static constexpr int ROW_IN  = 160;   // 64 scalars + 32*3 vectors
static constexpr int ROW_OUT = 160;   // 64 + 32*3

// constants (C_SV1*INV_SQRT3 == sqrt(1/128) == C_SS0; C_VS1*INV_SQRT3 == 1/8)
static constexpr float C_SS0_F    = 0.08838834764831845f; // sqrt(1/128)
static constexpr float C_VV0_I3_F = 0.07216878364870323f; // sqrt(1/64)/sqrt(3)
static constexpr float C_SV1_I3_F = 0.08838834764831845f; // sqrt(3/128)/sqrt(3)
static constexpr float C_VS1_I3_F = 0.125f;               // sqrt(3/64)/sqrt(3)

__device__ __forceinline__ floatx4 mfma16(bf16x8 a, bf16x8 b, floatx4 c) {
    return __builtin_amdgcn_mfma_f32_16x16x32_bf16(a, b, c, 0, 0, 0);
}

// Layout symmetry exploited here:
//   A-frag (16x16x32): lane holds A[m=lane&15][k=quad*8+j]
//   B-frag:            lane holds B[k=quad*8+j][n=lane&15]
// -> the SAME lane data serves either role. We put WEIGHTS in A and X in B, so
//   D[row=quad*4+r][col=lane&15] has row = output FEATURE (w), col = BATCH row.
// Each lane then owns 4 consecutive features of its own batch row => direct
// float4 global stores, x2 factors lane-local (no shfl), zero LDS, zero syncs.
__global__ __launch_bounds__(256, 2)
void o3tp_kernel(const float* __restrict__ x1, const float* __restrict__ x2,
                 const float* __restrict__ Wss0, const float* __restrict__ Wvv0,
                 const float* __restrict__ Wsv1, const float* __restrict__ Wvs1,
                 const float* __restrict__ bias0, float* __restrict__ out, int n)
{
    const int lane = threadIdx.x & 63;
    const int m = lane & 15;           // batch row within 16-tile (B-frag n / D col)
    const int q = lane >> 4;           // quad: k-slice (A/B) or feature-subrow group (D)

    // ---------- weight fragments (A-operands), built once per wave ----------
    // Identical indexing to a B-frag build: lane(m,q) elem j = W[u=k][w=ct*16+m].
    bf16x8 Wss[2][4];   // Wss0 (K=64 -> 2 k-tiles) x (64 feats -> 4 tiles)
    bf16x8 Wvv[4];      // Wvv0 (K=32) x 4 feat-tiles
    bf16x8 Wsv[2][2];   // Wsv1 (K=64) x 2 feat-tiles, scaled by C_SV1/sqrt3
    bf16x8 Wvs[2];      // Wvs1 (K=32) x 2 feat-tiles (scale folded into B)
#pragma unroll
    for (int kt = 0; kt < 2; ++kt)
#pragma unroll
        for (int ct = 0; ct < 4; ++ct)
#pragma unroll
            for (int j = 0; j < 8; ++j)
                Wss[kt][ct][j] = (__bf16)Wss0[(kt*32 + q*8 + j)*64 + ct*16 + m];
#pragma unroll
    for (int ct = 0; ct < 4; ++ct)
#pragma unroll
        for (int j = 0; j < 8; ++j)
            Wvv[ct][j] = (__bf16)Wvv0[(q*8 + j)*64 + ct*16 + m];
#pragma unroll
    for (int kt = 0; kt < 2; ++kt)
#pragma unroll
        for (int ct = 0; ct < 2; ++ct)
#pragma unroll
            for (int j = 0; j < 8; ++j)
                Wsv[kt][ct][j] = (__bf16)(Wsv1[(kt*32 + q*8 + j)*32 + ct*16 + m] * C_SV1_I3_F);
#pragma unroll
    for (int ct = 0; ct < 2; ++ct)
#pragma unroll
        for (int j = 0; j < 8; ++j)
            Wvs[ct][j] = (__bf16)Wvs1[(q*8 + j)*32 + ct*16 + m];

    // bias for features w = ct*16 + q*4 + r  (aligned float4 loads)
    floatx4 bias_v[4];
#pragma unroll
    for (int ct = 0; ct < 4; ++ct)
        bias_v[ct] = *(const floatx4*)(bias0 + ct*16 + q*4);

    const floatx4 zero = {0.f, 0.f, 0.f, 0.f};

    const int n_tiles = n >> 4;  // 400000/16 = 25000
    const int wid     = blockIdx.x * (blockDim.x >> 6) + (threadIdx.x >> 6);
    const int n_waves = gridDim.x * (blockDim.x >> 6);

    // ---- raw per-lane tile data (prefetched one tile ahead, pure registers) ----
    float4 rs[4];   // row m scalars: floats [kt*32+q*8 .. +8), kt=0 -> rs[0..1], kt=1 -> rs[2..3]
    float4 rc[6];   // row m vector part: floats [64+q*24 .. +24)
    float4 rx2;     // x2 row m

    auto LOAD = [&](int tile) {
        const float* __restrict__ src = x1 + (size_t)(tile*16 + m) * ROW_IN;
        rs[0] = *(const float4*)(src + q*8);
        rs[1] = *(const float4*)(src + q*8 + 4);
        rs[2] = *(const float4*)(src + 32 + q*8);
        rs[3] = *(const float4*)(src + 32 + q*8 + 4);
#pragma unroll
        for (int t = 0; t < 6; ++t)
            rc[t] = *(const float4*)(src + 64 + q*24 + t*4);
        rx2 = *(const float4*)(x2 + (size_t)(tile*16 + m) * 4);
    };

    int tile = wid;
    if (tile < n_tiles) LOAD(tile);

    for (; tile < n_tiles; ) {
        // ---- stage 1: raw regs -> fragments (B-operands), numerics identical to prior kernel ----
        bf16x8 a_s[2], a_ss[2];
        const float sscale = rx2.x * C_SS0_F;
#pragma unroll
        for (int kt = 0; kt < 2; ++kt) {
            const float vv[8] = {rs[2*kt].x, rs[2*kt].y, rs[2*kt].z, rs[2*kt].w,
                                 rs[2*kt+1].x, rs[2*kt+1].y, rs[2*kt+1].z, rs[2*kt+1].w};
#pragma unroll
            for (int j = 0; j < 8; ++j) {
                a_s[kt][j]  = (__bf16)vv[j];
                a_ss[kt][j] = (__bf16)(vv[j] * sscale);
            }
        }
        float c[24];
#pragma unroll
        for (int t = 0; t < 6; ++t) {
            c[t*4+0] = rc[t].x; c[t*4+1] = rc[t].y; c[t*4+2] = rc[t].z; c[t*4+3] = rc[t].w;
        }
        bf16x8 a_d, a_v0, a_v1, a_v2;
        const float gscale = rx2.x * C_VS1_I3_F;
        const float xy = rx2.y, xz = rx2.z, xw = rx2.w;   // keep: rx2 is overwritten by prefetch
#pragma unroll
        for (int j = 0; j < 8; ++j) {
            const float d = (c[3*j+0]*xy + c[3*j+1]*xz + c[3*j+2]*xw) * C_VV0_I3_F;
            a_d[j]  = (__bf16)d;
            a_v0[j] = (__bf16)(c[3*j+0] * gscale);
            a_v1[j] = (__bf16)(c[3*j+1] * gscale);
            a_v2[j] = (__bf16)(c[3*j+2] * gscale);
        }

        const int row0 = tile << 4;

        // ---- stage 2: prefetch next tile (latency hidden under MFMAs + epilogue) ----
        tile += n_waves;
        if (tile < n_tiles) LOAD(tile);

        // ---- stage 3: MFMAs (22, all K useful). Weights=A, x=B -> D[feature][batch] ----
        floatx4 acc0[4], accT[2], accG0[2], accG1[2], accG2[2];
#pragma unroll
        for (int ct = 0; ct < 4; ++ct) {
            acc0[ct] = mfma16(Wss[0][ct], a_ss[0], zero);
            acc0[ct] = mfma16(Wss[1][ct], a_ss[1], acc0[ct]);
            acc0[ct] = mfma16(Wvv[ct],    a_d,     acc0[ct]);
        }
#pragma unroll
        for (int ct = 0; ct < 2; ++ct) {
            accT[ct]  = mfma16(Wsv[0][ct], a_s[0], zero);
            accT[ct]  = mfma16(Wsv[1][ct], a_s[1], accT[ct]);
            accG0[ct] = mfma16(Wvs[ct], a_v0, zero);
            accG1[ct] = mfma16(Wvs[ct], a_v1, zero);
            accG2[ct] = mfma16(Wvs[ct], a_v2, zero);
        }

        // ---- stage 4: epilogue, direct coalesced float4 stores (no LDS, no shfl) ----
        // lane owns batch row (row0+m), features w = ct*16 + q*4 + r
        float* __restrict__ dst = out + (size_t)(row0 + m) * ROW_OUT;
#pragma unroll
        for (int ct = 0; ct < 4; ++ct) {
            floatx4 o;
#pragma unroll
            for (int r = 0; r < 4; ++r) o[r] = acc0[ct][r] + bias_v[ct][r];
            *(floatx4*)(dst + ct*16 + q*4) = o;
        }
#pragma unroll
        for (int ct = 0; ct < 2; ++ct) {
            float vals[12];   // features 64 + 48*ct + 12*q + (3r+i), 12 consecutive floats
#pragma unroll
            for (int r = 0; r < 4; ++r) {
                const float t = accT[ct][r];
                vals[3*r+0] = fmaf(xy, t, accG0[ct][r]);
                vals[3*r+1] = fmaf(xz, t, accG1[ct][r]);
                vals[3*r+2] = fmaf(xw, t, accG2[ct][r]);
            }
            float* __restrict__ p = dst + 64 + 48*ct + 12*q;
#pragma unroll
            for (int s = 0; s < 3; ++s) {
                floatx4 o = {vals[4*s+0], vals[4*s+1], vals[4*s+2], vals[4*s+3]};
                *(floatx4*)(p + 4*s) = o;
            }
        }
    }
}

extern "C" void kernel_launch(void* const* d_in, const int* in_sizes, int n_in,
                              void* d_out, int out_size, void* d_ws, size_t ws_size,
                              hipStream_t stream) {
    const float* x1    = (const float*)d_in[0];
    const float* x2    = (const float*)d_in[1];
    const float* Wss0  = (const float*)d_in[2];
    const float* Wvv0  = (const float*)d_in[3];
    const float* Wsv1  = (const float*)d_in[4];
    const float* Wvs1  = (const float*)d_in[5];
    const float* bias0 = (const float*)d_in[6];
    float* out = (float*)d_out;
    const int n = in_sizes[0] / ROW_IN;   // 400000

    // 512 blocks x 4 waves = 2048 waves (8/CU at 2 blocks/CU); ~12 tiles/wave
    // amortizes the one-time weight-fragment build. No LDS -> occupancy is VGPR-bound.
    dim3 grid(512), block(256);
    hipLaunchKernelGGL(o3tp_kernel, grid, block, 0, stream,
                       x1, x2, Wss0, Wvv0, Wsv1, Wvs1, bias0, out, n);
}